// Round 1
// baseline (439.976 us; speedup 1.0000x reference)
//
#include <hip/hip_runtime.h>
#include <cstdint>
#include <cstddef>

#define B_ 16
#define C_ 64
#define V_ 20000
#define L_ 9
#define O_ 64
#define K_ 576   // C_*L_
#define NBV (B_*V_)   // 320000

// ---------------------------------------------------------------------------
// K0a: transpose x[b][c][v] -> xT[(c*V+v)*16 + b]  (so 16 b's are contiguous)
__global__ __launch_bounds__(256) void k_transpose_x(const float* __restrict__ x,
                                                     float* __restrict__ xT) {
    int gid = blockIdx.x * blockDim.x + threadIdx.x;   // over C_*V_ (c*V+v)
    if (gid >= C_ * V_) return;
    float vals[B_];
#pragma unroll
    for (int b = 0; b < B_; ++b)
        vals[b] = x[(size_t)b * (C_ * V_) + gid];
    float4* dst = (float4*)(xT + (size_t)gid * B_);
#pragma unroll
    for (int q = 0; q < 4; ++q)
        dst[q] = make_float4(vals[q*4+0], vals[q*4+1], vals[q*4+2], vals[q*4+3]);
}

// K0b: Wt[k][o] = W[o][k]
__global__ __launch_bounds__(256) void k_transpose_w(const float* __restrict__ W,
                                                     float* __restrict__ Wt) {
    int gid = blockIdx.x * blockDim.x + threadIdx.x;   // over K_*O_
    if (gid >= K_ * O_) return;
    int k = gid / O_, o = gid % O_;
    Wt[gid] = W[o * K_ + k];
}

// ---------------------------------------------------------------------------
// K1: conv.  Block = 256 thr (4 waves), handles 16 v's, all 16 b, all 64 o.
// wave wv owns o in [wv*16, wv*16+16); lane = (v_local<<2) | (b0>>2).
// XT=true: read xT[(c*V+g)*16+b0] as float4 ; XT=false: 4 strided reads of x.
template<bool XT>
__global__ __launch_bounds__(256) void k_conv(const float* __restrict__ xsrc,
                                              const int*   __restrict__ S,
                                              const float* __restrict__ Wt,
                                              const float* __restrict__ bias,
                                              float* __restrict__ out) {
    const int vt   = blockIdx.x;          // 0..1249
    const int tid  = threadIdx.x;
    const int wv   = tid >> 6;
    const int lane = tid & 63;
    const int o0   = __builtin_amdgcn_readfirstlane(wv << 4);
    const int v    = vt * 16 + (lane >> 2);
    const int b0   = (lane & 3) << 2;

    // effective gather indices: g_t(v) = S_flat[t*V + v]
    int gt[L_];
#pragma unroll
    for (int t = 0; t < L_; ++t) gt[t] = S[t * V_ + v];

    float acc[16][4];
#pragma unroll
    for (int i = 0; i < 16; ++i)
#pragma unroll
        for (int j = 0; j < 4; ++j) acc[i][j] = 0.f;

    for (int c = 0; c < C_; ++c) {
        float4 xv[L_];
#pragma unroll
        for (int t = 0; t < L_; ++t) {
            if (XT) {
                xv[t] = *(const float4*)(xsrc + ((size_t)(c * V_ + gt[t])) * B_ + b0);
            } else {
                float tmp[4];
#pragma unroll
                for (int j = 0; j < 4; ++j)
                    tmp[j] = xsrc[((size_t)(b0 + j) * C_ + c) * V_ + gt[t]];
                xv[t] = make_float4(tmp[0], tmp[1], tmp[2], tmp[3]);
            }
        }
        const float* wrow = Wt + (size_t)(c * L_) * O_ + o0;   // wave-uniform base
#pragma unroll
        for (int t = 0; t < L_; ++t) {
#pragma unroll
            for (int i = 0; i < 16; ++i) {
                const float w = wrow[t * O_ + i];              // scalar load
                acc[i][0] = fmaf(w, xv[t].x, acc[i][0]);
                acc[i][1] = fmaf(w, xv[t].y, acc[i][1]);
                acc[i][2] = fmaf(w, xv[t].z, acc[i][2]);
                acc[i][3] = fmaf(w, xv[t].w, acc[i][3]);
            }
        }
    }

#pragma unroll
    for (int i = 0; i < 16; ++i) {
        const float bo = bias[o0 + i];
#pragma unroll
        for (int j = 0; j < 4; ++j)
            out[((size_t)(b0 + j) * O_ + (o0 + i)) * V_ + v] = acc[i][j] + bo;
    }
}

// ---------------------------------------------------------------------------
// K2: per-(o,slab) partial sums of out and out^2.  20 slabs of 1000 v's.
__global__ __launch_bounds__(256) void k_stats(const float* __restrict__ out,
                                               float* __restrict__ part) {
    const int o    = blockIdx.x & 63;
    const int slab = blockIdx.x >> 6;      // 0..19
    const int tid  = threadIdx.x;
    float s = 0.f, q = 0.f;
    for (int b = 0; b < B_; ++b) {
        const float4* p = (const float4*)(out + ((size_t)(b * O_ + o)) * V_ + slab * 1000);
        for (int i = tid; i < 250; i += 256) {   // 250 float4 = 1000 floats
            float4 v4 = p[i];
            s += v4.x + v4.y + v4.z + v4.w;
            q += v4.x*v4.x + v4.y*v4.y + v4.z*v4.z + v4.w*v4.w;
        }
    }
#pragma unroll
    for (int off = 32; off; off >>= 1) {
        s += __shfl_down(s, off);
        q += __shfl_down(q, off);
    }
    __shared__ float ls[4], lq[4];
    const int wv = tid >> 6, lane = tid & 63;
    if (lane == 0) { ls[wv] = s; lq[wv] = q; }
    __syncthreads();
    if (tid == 0) {
        float S4 = ls[0] + ls[1] + ls[2] + ls[3];
        float Q4 = lq[0] + lq[1] + lq[2] + lq[3];
        part[(slab * 64 + o) * 2 + 0] = S4;
        part[(slab * 64 + o) * 2 + 1] = Q4;
    }
}

// K2b: finalize -> scale/shift per o
__global__ void k_finalize(const float* __restrict__ part,
                           const float* __restrict__ gamma,
                           const float* __restrict__ beta,
                           float* __restrict__ ss) {
    int o = threadIdx.x;
    if (o >= O_) return;
    float s = 0.f, q = 0.f;
    for (int sl = 0; sl < 20; ++sl) {
        s += part[(sl * 64 + o) * 2 + 0];
        q += part[(sl * 64 + o) * 2 + 1];
    }
    const float n = 1.f / (float)NBV;
    float mean = s * n;
    float var  = fmaxf(q * n - mean * mean, 0.f);
    float rstd = rsqrtf(var + 1e-5f);
    float sc   = gamma[o] * rstd;
    ss[o]      = sc;
    ss[O_ + o] = beta[o] - mean * sc;
}

// K3: in-place normalize + relu
__global__ __launch_bounds__(256) void k_norm(float* __restrict__ out,
                                              const float* __restrict__ ss) {
    const int stride = gridDim.x * blockDim.x;
    const int total4 = (B_ * O_ * V_) / 4;
    for (int i = blockIdx.x * blockDim.x + threadIdx.x; i < total4; i += stride) {
        float4 v4 = ((const float4*)out)[i];
        const int row = (i * 4) / V_;     // b*64 + o  (V_ % 4 == 0 -> uniform per float4)
        const int o   = row & 63;
        const float sc = ss[o], sh = ss[O_ + o];
        v4.x = fmaxf(fmaf(v4.x, sc, sh), 0.f);
        v4.y = fmaxf(fmaf(v4.y, sc, sh), 0.f);
        v4.z = fmaxf(fmaf(v4.z, sc, sh), 0.f);
        v4.w = fmaxf(fmaf(v4.w, sc, sh), 0.f);
        ((float4*)out)[i] = v4;
    }
}

// ---------------------------------------------------------------------------
extern "C" void kernel_launch(void* const* d_in, const int* in_sizes, int n_in,
                              void* d_out, int out_size, void* d_ws, size_t ws_size,
                              hipStream_t stream) {
    const float* x     = (const float*)d_in[0];
    const int*   S     = (const int*)  d_in[1];
    const float* W     = (const float*)d_in[2];
    const float* bias  = (const float*)d_in[3];
    const float* gamma = (const float*)d_in[4];
    const float* beta  = (const float*)d_in[5];
    float* out = (float*)d_out;

    const size_t xT_bytes   = (size_t)C_ * V_ * B_ * sizeof(float);   // 81.92 MB
    const size_t wt_bytes   = (size_t)K_ * O_ * sizeof(float);        // 147 KB
    const size_t part_bytes = (size_t)20 * 64 * 2 * sizeof(float);
    const size_t ss_bytes   = (size_t)2 * O_ * sizeof(float);

    char* ws = (char*)d_ws;
    const bool use_xt = ws_size >= xT_bytes + wt_bytes + part_bytes + ss_bytes;

    size_t off = 0;
    float* xT = nullptr;
    if (use_xt) { xT = (float*)(ws + off); off += xT_bytes; }
    float* Wt   = (float*)(ws + off); off += wt_bytes;
    float* part = (float*)(ws + off); off += part_bytes;
    float* ss   = (float*)(ws + off);

    k_transpose_w<<<dim3((K_ * O_ + 255) / 256), dim3(256), 0, stream>>>(W, Wt);

    if (use_xt) {
        k_transpose_x<<<dim3((C_ * V_) / 256), dim3(256), 0, stream>>>(x, xT);
        k_conv<true><<<dim3(V_ / 16), dim3(256), 0, stream>>>(xT, S, Wt, bias, out);
    } else {
        k_conv<false><<<dim3(V_ / 16), dim3(256), 0, stream>>>(x, S, Wt, bias, out);
    }

    k_stats<<<dim3(64 * 20), dim3(256), 0, stream>>>(out, part);
    k_finalize<<<dim3(1), dim3(64), 0, stream>>>(part, gamma, beta, ss);
    k_norm<<<dim3(2048), dim3(256), 0, stream>>>(out, ss);
}

// Round 2
// 132.649 us; speedup vs baseline: 3.3169x; 3.3169x over previous
//
#include <hip/hip_runtime.h>
#include <hip/hip_bf16.h>
#include <cstdint>
#include <cstddef>

#define B_ 16
#define C_ 64
#define V_ 20000
#define L_ 9
#define O_ 64
#define K_ 576          // C_*L_
#define NBV (B_*V_)     // 320000

typedef short bf16x8 __attribute__((ext_vector_type(8)));
typedef float f32x4  __attribute__((ext_vector_type(4)));

__device__ inline unsigned short f2bf(float f) {
    union { float f; unsigned u; } x; x.f = f;
    unsigned r = (x.u + 0x7fffu + ((x.u >> 16) & 1u)) >> 16;   // RNE
    return (unsigned short)r;
}

// ---------------------------------------------------------------------------
// K0a: x[b][c][v] (f32) -> xTb[b][v][c] (bf16). Row (b,v) = 64 ushorts = 128 B.
// grid (625, 16): blockIdx.x = v-tile of 32, blockIdx.y = b.
__global__ __launch_bounds__(256) void k_tx(const float* __restrict__ x,
                                            ushort* __restrict__ xTb) {
    __shared__ float t[C_][33];
    const int b  = blockIdx.y;
    const int v0 = blockIdx.x * 32;
    const int tid = threadIdx.x;

    { // load 64c x 32v tile, coalesced over v
        const int c  = tid >> 2;
        const int jj = tid & 3;
        const float* src = x + ((size_t)b * C_ + c) * V_ + v0 + jj * 8;
        float4 f0 = ((const float4*)src)[0];
        float4 f1 = ((const float4*)src)[1];
        t[c][jj*8+0] = f0.x; t[c][jj*8+1] = f0.y; t[c][jj*8+2] = f0.z; t[c][jj*8+3] = f0.w;
        t[c][jj*8+4] = f1.x; t[c][jj*8+5] = f1.y; t[c][jj*8+6] = f1.z; t[c][jj*8+7] = f1.w;
    }
    __syncthreads();
    { // store transposed, bf16, 16 B per thread
        const int vl = tid & 31;
        const int cg = tid >> 5;          // 0..7, 8 c's each
        union { ushort u[8]; uint4 v4; } pk;
#pragma unroll
        for (int i = 0; i < 8; ++i) pk.u[i] = f2bf(t[cg*8 + i][vl]);
        *(uint4*)(xTb + ((size_t)(b * V_ + v0 + vl)) * 64 + cg * 8) = pk.v4;
    }
}

// K0b: Wtb[o][k' = t*64 + c] = bf16(W[o][c*9 + t])
__global__ __launch_bounds__(256) void k_tw(const float* __restrict__ W,
                                            ushort* __restrict__ Wtb) {
    int gid = blockIdx.x * 256 + threadIdx.x;
    if (gid >= O_ * K_) return;
    int o = gid / K_, kp = gid % K_;
    int tt = kp >> 6, c = kp & 63;
    Wtb[gid] = f2bf(W[o * K_ + c * L_ + tt]);
}

// ---------------------------------------------------------------------------
// K1: MFMA conv. Block = 512 thr (8 waves), 16 v's, all 16 b (n = b*16+vl, 256
// rows), all 64 o. K' = t*64+c, 18 K-steps of 32, double-buffered LDS.
// LDS tiles: neigh[256 rows][64 B] + W[64 rows][64 B], slot-swizzled
// (pos = slot ^ ((row>>1)&3)) so frag ds_read_b128 is 2-way (free).
__global__ __launch_bounds__(512, 4) void k_conv(const ushort* __restrict__ xTb,
                                                 const int*    __restrict__ S,
                                                 const ushort* __restrict__ Wtb,
                                                 const float*  __restrict__ bias,
                                                 float* __restrict__ out,
                                                 float* __restrict__ ps,
                                                 float* __restrict__ pq) {
    __shared__ char lds[45056];
    char* nbA = lds;            char* wbA = lds + 16384;
    char* nbB = lds + 20480;    char* wbB = lds + 36864;
    float* sA = (float*)(lds + 40960);   // [64][8]
    float* sQ = (float*)(lds + 43008);   // [64][8]

    const int tid = threadIdx.x;
    const int v0  = blockIdx.x * 16;
    // staging ids (neigh: 2 threads per row, 64 B each per K-iter-pair)
    const int srow = tid >> 1;            // n row 0..255
    const int h    = tid & 1;
    const int sb   = srow >> 4;           // b
    const int sv   = v0 + (srow & 15);    // v
    const int swzn = (srow >> 1) & 3;
    // staging ids (W: tid<256, 1 slot per step)
    const int so    = tid >> 2;           // o row
    const int wslot = tid & 3;
    const int swzo  = (so >> 1) & 3;
    // mfma ids
    const int w = tid >> 6;               // wave 0..7
    const int l = tid & 63;
    const int q = l >> 4;
    const int r = l & 15;
    const int fswz = (r >> 1) & 3;        // frag-read swizzle (rows = X*16 + r)

    f32x4 acc[2][4];
#pragma unroll
    for (int nt = 0; nt < 2; ++nt)
#pragma unroll
        for (int ot = 0; ot < 4; ++ot) acc[nt][ot] = (f32x4){0.f, 0.f, 0.f, 0.f};

    uint4 rn0 = {0,0,0,0}, rn1 = {0,0,0,0}, rn2 = {0,0,0,0}, rn3 = {0,0,0,0};
    uint4 rw0 = {0,0,0,0}, rw1 = {0,0,0,0};

    auto LD = [&](int i) {
        int g = S[i * V_ + sv];
        const uint4* p = (const uint4*)(xTb + ((size_t)sb * V_ + g) * 64 + h * 16);
        rn0 = p[0]; rn1 = p[1];          // step even (c 0..31), this thread's 32 B
        rn2 = p[4]; rn3 = p[5];          // step odd  (c 32..63)
        if (tid < 256) {
            const uint4* wp = (const uint4*)(Wtb + (size_t)so * K_ + i * 64 + wslot * 8);
            rw0 = wp[0];                 // step even slot
            rw1 = wp[4];                 // step odd slot (+32 k = +64 B)
        }
    };
    auto WRN = [&](char* nb, uint4 a, uint4 b2) {
        char* base = nb + srow * 64;
        *(uint4*)(base + ((( 2*h   ) ^ swzn) << 4)) = a;
        *(uint4*)(base + (((2*h + 1) ^ swzn) << 4)) = b2;
    };
    auto WRW = [&](char* wb, uint4 a) {
        if (tid < 256) *(uint4*)(wb + so * 64 + ((wslot ^ swzo) << 4)) = a;
    };
    auto MM = [&](const char* nb, const char* wb) {
        bf16x8 a0 = *(const bf16x8*)(nb + (w*32      + r) * 64 + ((q ^ fswz) << 4));
        bf16x8 a1 = *(const bf16x8*)(nb + (w*32 + 16 + r) * 64 + ((q ^ fswz) << 4));
#pragma unroll
        for (int ot = 0; ot < 4; ++ot) {
            bf16x8 bo = *(const bf16x8*)(wb + (ot*16 + r) * 64 + ((q ^ fswz) << 4));
            acc[0][ot] = __builtin_amdgcn_mfma_f32_16x16x32_bf16(a0, bo, acc[0][ot], 0, 0, 0);
            acc[1][ot] = __builtin_amdgcn_mfma_f32_16x16x32_bf16(a1, bo, acc[1][ot], 0, 0, 0);
        }
    };

    LD(0);
#pragma unroll
    for (int i = 0; i < 9; ++i) {
        WRN(nbA, rn0, rn1); WRW(wbA, rw0);
        __syncthreads();
        MM(nbA, wbA);
        WRN(nbB, rn2, rn3); WRW(wbB, rw1);
        if (i < 8) LD(i + 1);
        __syncthreads();
        MM(nbB, wbB);
    }

    // epilogue: y = acc + bias -> store + fused partial stats
    const int vbase = v0 + q * 4;
    float ssum[4] = {0.f, 0.f, 0.f, 0.f};
    float qsum[4] = {0.f, 0.f, 0.f, 0.f};
#pragma unroll
    for (int ot = 0; ot < 4; ++ot) {
        const int o = ot * 16 + r;
        const float bo = bias[o];
#pragma unroll
        for (int nt = 0; nt < 2; ++nt) {
            const int b = 2 * w + nt;
            float4 y;
            y.x = acc[nt][ot][0] + bo;
            y.y = acc[nt][ot][1] + bo;
            y.z = acc[nt][ot][2] + bo;
            y.w = acc[nt][ot][3] + bo;
            *(float4*)(out + ((size_t)(b * O_ + o)) * V_ + vbase) = y;
            ssum[ot] += y.x + y.y + y.z + y.w;
            qsum[ot] += y.x*y.x + y.y*y.y + y.z*y.z + y.w*y.w;
        }
    }
#pragma unroll
    for (int ot = 0; ot < 4; ++ot) {
        float s  = ssum[ot], qq = qsum[ot];
        s  += __shfl_xor(s, 16);  s  += __shfl_xor(s, 32);
        qq += __shfl_xor(qq, 16); qq += __shfl_xor(qq, 32);
        if (l < 16) { sA[(ot*16 + l) * 8 + w] = s; sQ[(ot*16 + l) * 8 + w] = qq; }
    }
    __syncthreads();
    if (tid < 64) {
        float s = 0.f, qq = 0.f;
#pragma unroll
        for (int j = 0; j < 8; ++j) { s += sA[tid*8 + j]; qq += sQ[tid*8 + j]; }
        ps[blockIdx.x * 64 + tid] = s;
        pq[blockIdx.x * 64 + tid] = qq;
    }
}

// ---------------------------------------------------------------------------
// K2: reduce 1250 block-partials per o -> scale/shift
__global__ __launch_bounds__(256) void k_fin(const float* __restrict__ ps,
                                             const float* __restrict__ pq,
                                             const float* __restrict__ gamma,
                                             const float* __restrict__ beta,
                                             float* __restrict__ ss) {
    __shared__ float as_[4], aq_[4];
    const int o = blockIdx.x, tid = threadIdx.x;
    float s = 0.f, q = 0.f;
    for (int i = tid; i < 1250; i += 256) { s += ps[i*64 + o]; q += pq[i*64 + o]; }
#pragma unroll
    for (int off = 1; off < 64; off <<= 1) { s += __shfl_xor(s, off); q += __shfl_xor(q, off); }
    if ((tid & 63) == 0) { as_[tid >> 6] = s; aq_[tid >> 6] = q; }
    __syncthreads();
    if (tid == 0) {
        float S4 = as_[0] + as_[1] + as_[2] + as_[3];
        float Q4 = aq_[0] + aq_[1] + aq_[2] + aq_[3];
        const float n = 1.f / (float)NBV;
        float mean = S4 * n;
        float var  = fmaxf(Q4 * n - mean * mean, 0.f);
        float sc   = gamma[o] * rsqrtf(var + 1e-5f);
        ss[o]      = sc;
        ss[O_ + o] = beta[o] - mean * sc;
    }
}

// K3: in-place normalize + relu
__global__ __launch_bounds__(256) void k_norm(float* __restrict__ out,
                                              const float* __restrict__ ss) {
    const int stride = gridDim.x * blockDim.x;
    const int total4 = (B_ * O_ * V_) / 4;
    for (int i = blockIdx.x * blockDim.x + threadIdx.x; i < total4; i += stride) {
        float4 v4 = ((const float4*)out)[i];
        const int row = (i * 4) / V_;       // b*64 + o (V_%4==0 -> uniform per float4)
        const int o   = row & 63;
        const float sc = ss[o], sh = ss[O_ + o];
        v4.x = fmaxf(fmaf(v4.x, sc, sh), 0.f);
        v4.y = fmaxf(fmaf(v4.y, sc, sh), 0.f);
        v4.z = fmaxf(fmaf(v4.z, sc, sh), 0.f);
        v4.w = fmaxf(fmaf(v4.w, sc, sh), 0.f);
        ((float4*)out)[i] = v4;
    }
}

// ---------------------------------------------------------------------------
extern "C" void kernel_launch(void* const* d_in, const int* in_sizes, int n_in,
                              void* d_out, int out_size, void* d_ws, size_t ws_size,
                              hipStream_t stream) {
    const float* x     = (const float*)d_in[0];
    const int*   S     = (const int*)  d_in[1];
    const float* W     = (const float*)d_in[2];
    const float* bias  = (const float*)d_in[3];
    const float* gamma = (const float*)d_in[4];
    const float* beta  = (const float*)d_in[5];
    float* out = (float*)d_out;

    char* ws = (char*)d_ws;
    ushort* xTb = (ushort*)(ws);                       // 16*20000*64*2 = 40,960,000 B
    ushort* Wtb = (ushort*)(ws + 40960000);            // 73,728 B
    float*  ps  = (float*) (ws + 41033728);            // 1250*64*4 = 320,000 B
    float*  pq  = (float*) (ws + 41353728);            // 320,000 B
    float*  ssb = (float*) (ws + 41673728);            // 512 B

    k_tw  <<<dim3((O_ * K_ + 255) / 256), dim3(256), 0, stream>>>(W, Wtb);
    k_tx  <<<dim3(625, 16),               dim3(256), 0, stream>>>(x, xTb);
    k_conv<<<dim3(V_ / 16),               dim3(512), 0, stream>>>(xTb, S, Wtb, bias, out, ps, pq);
    k_fin <<<dim3(64),                    dim3(256), 0, stream>>>(ps, pq, gamma, beta, ssb);
    k_norm<<<dim3(2048),                  dim3(256), 0, stream>>>(out, ssb);
}

// Round 3
// 118.591 us; speedup vs baseline: 3.7100x; 1.1185x over previous
//
#include <hip/hip_runtime.h>
#include <hip/hip_bf16.h>
#include <cstdint>
#include <cstddef>

#define B_ 16
#define C_ 64
#define V_ 20000
#define L_ 9
#define O_ 64
#define K_ 576          // C_*L_
#define NBV (B_*V_)     // 320000

typedef short bf16x8 __attribute__((ext_vector_type(8)));
typedef float f32x4  __attribute__((ext_vector_type(4)));

__device__ inline unsigned short f2bf(float f) {
    union { float f; unsigned u; } x; x.f = f;
    unsigned r = (x.u + 0x7fffu + ((x.u >> 16) & 1u)) >> 16;   // RNE
    return (unsigned short)r;
}

// ---------------------------------------------------------------------------
// K0a: x[b][c][v] (f32) -> xTb[b][v][c] (bf16). Row (b,v) = 64 ushorts = 128 B.
__global__ __launch_bounds__(256) void k_tx(const float* __restrict__ x,
                                            ushort* __restrict__ xTb) {
    __shared__ float t[C_][33];
    const int b  = blockIdx.y;
    const int v0 = blockIdx.x * 32;
    const int tid = threadIdx.x;

    {
        const int c  = tid >> 2;
        const int jj = tid & 3;
        const float* src = x + ((size_t)b * C_ + c) * V_ + v0 + jj * 8;
        float4 f0 = ((const float4*)src)[0];
        float4 f1 = ((const float4*)src)[1];
        t[c][jj*8+0] = f0.x; t[c][jj*8+1] = f0.y; t[c][jj*8+2] = f0.z; t[c][jj*8+3] = f0.w;
        t[c][jj*8+4] = f1.x; t[c][jj*8+5] = f1.y; t[c][jj*8+6] = f1.z; t[c][jj*8+7] = f1.w;
    }
    __syncthreads();
    {
        const int vl = tid & 31;
        const int cg = tid >> 5;
        union { ushort u[8]; uint4 v4; } pk;
#pragma unroll
        for (int i = 0; i < 8; ++i) pk.u[i] = f2bf(t[cg*8 + i][vl]);
        *(uint4*)(xTb + ((size_t)(b * V_ + v0 + vl)) * 64 + cg * 8) = pk.v4;
    }
}

// K0b: Wtb[o][k' = t*64 + c] = bf16(W[o][c*9 + t])
__global__ __launch_bounds__(256) void k_tw(const float* __restrict__ W,
                                            ushort* __restrict__ Wtb) {
    int gid = blockIdx.x * 256 + threadIdx.x;
    if (gid >= O_ * K_) return;
    int o = gid / K_, kp = gid % K_;
    int tt = kp >> 6, c = kp & 63;
    Wtb[gid] = f2bf(W[o * K_ + c * L_ + tt]);
}

// ---------------------------------------------------------------------------
// K1: MFMA conv. 512 thr (8 waves), 16 v, all 16 b (256 n-rows), all 64 o.
// K' = t*64+c, 9 t-iters x 2 K-steps, double-buffered LDS, depth-2 t-prefetch.
template<bool BF16Y>
__global__ __launch_bounds__(512, 4) void k_conv(const ushort* __restrict__ xTb,
                                                 const int*    __restrict__ S,
                                                 const ushort* __restrict__ Wtb,
                                                 const float*  __restrict__ bias,
                                                 float*  __restrict__ out,
                                                 ushort* __restrict__ yb,
                                                 float* __restrict__ ps,
                                                 float* __restrict__ pq) {
    __shared__ char lds[45056];
    char* nbA = lds;            char* wbA = lds + 16384;
    char* nbB = lds + 20480;    char* wbB = lds + 36864;
    float* sA = (float*)(lds + 40960);   // [64][8]
    float* sQ = (float*)(lds + 43008);   // [64][8]

    const int tid = threadIdx.x;
    const int v0  = blockIdx.x * 16;
    const int srow = tid >> 1;            // n row 0..255
    const int h    = tid & 1;
    const int sb   = srow >> 4;           // b
    const int sv   = v0 + (srow & 15);    // v
    const int swzn = (srow >> 1) & 3;
    const int so    = tid >> 2;           // W o row
    const int wslot = tid & 3;
    const int swzo  = (so >> 1) & 3;
    const int w = tid >> 6;               // wave 0..7
    const int l = tid & 63;
    const int q = l >> 4;
    const int r = l & 15;
    const int fswz = (r >> 1) & 3;

    f32x4 acc[2][4];
#pragma unroll
    for (int nt = 0; nt < 2; ++nt)
#pragma unroll
        for (int ot = 0; ot < 4; ++ot) acc[nt][ot] = (f32x4){0.f, 0.f, 0.f, 0.f};

    uint4 rn[2][4];
    uint4 rw[2][2];
#pragma unroll
    for (int s2 = 0; s2 < 2; ++s2) {
#pragma unroll
        for (int j = 0; j < 4; ++j) rn[s2][j] = make_uint4(0,0,0,0);
#pragma unroll
        for (int j = 0; j < 2; ++j) rw[s2][j] = make_uint4(0,0,0,0);
    }

    auto LD = [&](int i, int set) {
        int g = S[i * V_ + sv];
        const uint4* p = (const uint4*)(xTb + ((size_t)sb * V_ + g) * 64 + h * 16);
        rn[set][0] = p[0]; rn[set][1] = p[1];   // step even (c 0..31)
        rn[set][2] = p[4]; rn[set][3] = p[5];   // step odd  (c 32..63)
        if (tid < 256) {
            const uint4* wp = (const uint4*)(Wtb + (size_t)so * K_ + i * 64 + wslot * 8);
            rw[set][0] = wp[0];
            rw[set][1] = wp[4];
        }
    };
    auto WRN = [&](char* nb, uint4 a, uint4 b2) {
        char* base = nb + srow * 64;
        *(uint4*)(base + ((( 2*h   ) ^ swzn) << 4)) = a;
        *(uint4*)(base + (((2*h + 1) ^ swzn) << 4)) = b2;
    };
    auto WRW = [&](char* wb, uint4 a) {
        if (tid < 256) *(uint4*)(wb + so * 64 + ((wslot ^ swzo) << 4)) = a;
    };
    auto MM = [&](const char* nb, const char* wb) {
        bf16x8 a0 = *(const bf16x8*)(nb + (w*32      + r) * 64 + ((q ^ fswz) << 4));
        bf16x8 a1 = *(const bf16x8*)(nb + (w*32 + 16 + r) * 64 + ((q ^ fswz) << 4));
#pragma unroll
        for (int ot = 0; ot < 4; ++ot) {
            bf16x8 bo = *(const bf16x8*)(wb + (ot*16 + r) * 64 + ((q ^ fswz) << 4));
            acc[0][ot] = __builtin_amdgcn_mfma_f32_16x16x32_bf16(a0, bo, acc[0][ot], 0, 0, 0);
            acc[1][ot] = __builtin_amdgcn_mfma_f32_16x16x32_bf16(a1, bo, acc[1][ot], 0, 0, 0);
        }
    };

    LD(0, 0);
    LD(1, 1);
#pragma unroll
    for (int i = 0; i < 9; ++i) {
        const int set = i & 1;
        WRN(nbA, rn[set][0], rn[set][1]); WRW(wbA, rw[set][0]);
        __syncthreads();
        MM(nbA, wbA);
        WRN(nbB, rn[set][2], rn[set][3]); WRW(wbB, rw[set][1]);
        if (i < 7) LD(i + 2, set);        // depth-2 prefetch
        __syncthreads();
        MM(nbB, wbB);
    }

    // epilogue: y = acc + bias -> store (bf16 or f32) + fused partial stats
    const int vbase = v0 + q * 4;
    float ssum[4] = {0.f, 0.f, 0.f, 0.f};
    float qsum[4] = {0.f, 0.f, 0.f, 0.f};
#pragma unroll
    for (int ot = 0; ot < 4; ++ot) {
        const int o = ot * 16 + r;
        const float bo = bias[o];
#pragma unroll
        for (int nt = 0; nt < 2; ++nt) {
            const int b = 2 * w + nt;
            float4 y;
            y.x = acc[nt][ot][0] + bo;
            y.y = acc[nt][ot][1] + bo;
            y.z = acc[nt][ot][2] + bo;
            y.w = acc[nt][ot][3] + bo;
            if (BF16Y) {
                ushort4 u;
                u.x = f2bf(y.x); u.y = f2bf(y.y); u.z = f2bf(y.z); u.w = f2bf(y.w);
                *(ushort4*)(yb + ((size_t)(b * O_ + o)) * V_ + vbase) = u;
            } else {
                *(float4*)(out + ((size_t)(b * O_ + o)) * V_ + vbase) = y;
            }
            ssum[ot] += y.x + y.y + y.z + y.w;
            qsum[ot] += y.x*y.x + y.y*y.y + y.z*y.z + y.w*y.w;
        }
    }
#pragma unroll
    for (int ot = 0; ot < 4; ++ot) {
        float s  = ssum[ot], qq = qsum[ot];
        s  += __shfl_xor(s, 16);  s  += __shfl_xor(s, 32);
        qq += __shfl_xor(qq, 16); qq += __shfl_xor(qq, 32);
        if (l < 16) { sA[(ot*16 + l) * 8 + w] = s; sQ[(ot*16 + l) * 8 + w] = qq; }
    }
    __syncthreads();
    if (tid < 64) {
        float s = 0.f, qq = 0.f;
#pragma unroll
        for (int j = 0; j < 8; ++j) { s += sA[tid*8 + j]; qq += sQ[tid*8 + j]; }
        ps[blockIdx.x * 64 + tid] = s;
        pq[blockIdx.x * 64 + tid] = qq;
    }
}

// ---------------------------------------------------------------------------
// K2: reduce 1250 block-partials per o -> scale/shift
__global__ __launch_bounds__(256) void k_fin(const float* __restrict__ ps,
                                             const float* __restrict__ pq,
                                             const float* __restrict__ gamma,
                                             const float* __restrict__ beta,
                                             float* __restrict__ ss) {
    __shared__ float as_[4], aq_[4];
    const int o = blockIdx.x, tid = threadIdx.x;
    float s = 0.f, q = 0.f;
    for (int i = tid; i < 1250; i += 256) { s += ps[i*64 + o]; q += pq[i*64 + o]; }
#pragma unroll
    for (int off = 1; off < 64; off <<= 1) { s += __shfl_xor(s, off); q += __shfl_xor(q, off); }
    if ((tid & 63) == 0) { as_[tid >> 6] = s; aq_[tid >> 6] = q; }
    __syncthreads();
    if (tid == 0) {
        float S4 = as_[0] + as_[1] + as_[2] + as_[3];
        float Q4 = aq_[0] + aq_[1] + aq_[2] + aq_[3];
        const float n = 1.f / (float)NBV;
        float mean = S4 * n;
        float var  = fmaxf(Q4 * n - mean * mean, 0.f);
        float sc   = gamma[o] * rsqrtf(var + 1e-5f);
        ss[o]      = sc;
        ss[O_ + o] = beta[o] - mean * sc;
    }
}

// K3a: normalize + relu from bf16 y -> f32 out
__global__ __launch_bounds__(256) void k_norm_bf(const ushort* __restrict__ yb,
                                                 float* __restrict__ out,
                                                 const float* __restrict__ ss) {
    const int stride = gridDim.x * blockDim.x;
    const int total8 = (B_ * O_ * V_) / 8;
    for (int i = blockIdx.x * blockDim.x + threadIdx.x; i < total8; i += stride) {
        uint4 raw = ((const uint4*)yb)[i];
        const int row = (i * 8) / V_;       // b*64 + o (V_%8==0 -> uniform)
        const int o   = row & 63;
        const float sc = ss[o], sh = ss[O_ + o];
        const uint u32[4] = {raw.x, raw.y, raw.z, raw.w};
        float4 o0, o1;
        float vals[8];
#pragma unroll
        for (int j = 0; j < 4; ++j) {
            union { uint u; float f; } lo, hi;
            lo.u = (u32[j] & 0xffffu) << 16;
            hi.u = (u32[j] & 0xffff0000u);
            vals[2*j]   = lo.f;
            vals[2*j+1] = hi.f;
        }
        o0.x = fmaxf(fmaf(vals[0], sc, sh), 0.f);
        o0.y = fmaxf(fmaf(vals[1], sc, sh), 0.f);
        o0.z = fmaxf(fmaf(vals[2], sc, sh), 0.f);
        o0.w = fmaxf(fmaf(vals[3], sc, sh), 0.f);
        o1.x = fmaxf(fmaf(vals[4], sc, sh), 0.f);
        o1.y = fmaxf(fmaf(vals[5], sc, sh), 0.f);
        o1.z = fmaxf(fmaf(vals[6], sc, sh), 0.f);
        o1.w = fmaxf(fmaf(vals[7], sc, sh), 0.f);
        ((float4*)out)[2*i]   = o0;
        ((float4*)out)[2*i+1] = o1;
    }
}

// K3b: fallback, in-place f32 normalize + relu
__global__ __launch_bounds__(256) void k_norm_f32(float* __restrict__ out,
                                                  const float* __restrict__ ss) {
    const int stride = gridDim.x * blockDim.x;
    const int total4 = (B_ * O_ * V_) / 4;
    for (int i = blockIdx.x * blockDim.x + threadIdx.x; i < total4; i += stride) {
        float4 v4 = ((const float4*)out)[i];
        const int row = (i * 4) / V_;
        const int o   = row & 63;
        const float sc = ss[o], sh = ss[O_ + o];
        v4.x = fmaxf(fmaf(v4.x, sc, sh), 0.f);
        v4.y = fmaxf(fmaf(v4.y, sc, sh), 0.f);
        v4.z = fmaxf(fmaf(v4.z, sc, sh), 0.f);
        v4.w = fmaxf(fmaf(v4.w, sc, sh), 0.f);
        ((float4*)out)[i] = v4;
    }
}

// ---------------------------------------------------------------------------
extern "C" void kernel_launch(void* const* d_in, const int* in_sizes, int n_in,
                              void* d_out, int out_size, void* d_ws, size_t ws_size,
                              hipStream_t stream) {
    const float* x     = (const float*)d_in[0];
    const int*   S     = (const int*)  d_in[1];
    const float* W     = (const float*)d_in[2];
    const float* bias  = (const float*)d_in[3];
    const float* gamma = (const float*)d_in[4];
    const float* beta  = (const float*)d_in[5];
    float* out = (float*)d_out;

    char* ws = (char*)d_ws;
    const size_t xT_b = 40960000;            // 16*20000*64*2
    const size_t wt_b = 73728;               // 576*64*2
    const size_t yb_b = 40960000;            // 16*64*20000*2
    const size_t ps_b = 320000;              // 1250*64*4

    ushort* xTb = (ushort*)(ws);
    ushort* Wtb = (ushort*)(ws + xT_b);
    const bool bf16y = ws_size >= xT_b + wt_b + yb_b + 2 * ps_b + 512;

    ushort* yb; float* ps; float* pq; float* ssb;
    if (bf16y) {
        yb  = (ushort*)(ws + xT_b + wt_b);
        ps  = (float*) (ws + xT_b + wt_b + yb_b);
        pq  = (float*) (ws + xT_b + wt_b + yb_b + ps_b);
        ssb = (float*) (ws + xT_b + wt_b + yb_b + 2 * ps_b);
    } else {
        yb  = nullptr;
        ps  = (float*) (ws + xT_b + wt_b);
        pq  = (float*) (ws + xT_b + wt_b + ps_b);
        ssb = (float*) (ws + xT_b + wt_b + 2 * ps_b);
    }

    k_tw<<<dim3((O_ * K_ + 255) / 256), dim3(256), 0, stream>>>(W, Wtb);
    k_tx<<<dim3(625, 16),               dim3(256), 0, stream>>>(x, xTb);
    if (bf16y) {
        k_conv<true ><<<dim3(V_ / 16), dim3(512), 0, stream>>>(xTb, S, Wtb, bias, out, yb, ps, pq);
        k_fin<<<dim3(64), dim3(256), 0, stream>>>(ps, pq, gamma, beta, ssb);
        k_norm_bf<<<dim3(2048), dim3(256), 0, stream>>>(yb, out, ssb);
    } else {
        k_conv<false><<<dim3(V_ / 16), dim3(512), 0, stream>>>(xTb, S, Wtb, bias, out, yb, ps, pq);
        k_fin<<<dim3(64), dim3(256), 0, stream>>>(ps, pq, gamma, beta, ssb);
        k_norm_f32<<<dim3(2048), dim3(256), 0, stream>>>(out, ssb);
    }
}

// Round 4
// 116.832 us; speedup vs baseline: 3.7659x; 1.0151x over previous
//
#include <hip/hip_runtime.h>
#include <hip/hip_bf16.h>
#include <cstdint>
#include <cstddef>

#define B_ 16
#define C_ 64
#define V_ 20000
#define L_ 9
#define O_ 64
#define K_ 576          // C_*L_
#define NBV (B_*V_)     // 320000

typedef short bf16x8 __attribute__((ext_vector_type(8)));
typedef float f32x4  __attribute__((ext_vector_type(4)));

__device__ inline unsigned short f2bf(float f) {
    union { float f; unsigned u; } x; x.f = f;
    unsigned r = (x.u + 0x7fffu + ((x.u >> 16) & 1u)) >> 16;   // RNE
    return (unsigned short)r;
}

// raw barrier: retire LDS ops, then barrier — NO vmcnt drain (keeps prefetch in flight)
#define BARRIER() do { \
    asm volatile("s_waitcnt lgkmcnt(0)" ::: "memory"); \
    __builtin_amdgcn_s_barrier(); \
} while (0)
#define VMW(N) asm volatile("s_waitcnt vmcnt(" #N ")" ::: "memory")

// ---------------------------------------------------------------------------
// K0a: x[b][c][v] (f32) -> xTb[b][v][c] (bf16). Row (b,v) = 64 ushorts = 128 B.
__global__ __launch_bounds__(256) void k_tx(const float* __restrict__ x,
                                            ushort* __restrict__ xTb) {
    __shared__ float t[C_][33];
    const int b  = blockIdx.y;
    const int v0 = blockIdx.x * 32;
    const int tid = threadIdx.x;
    {
        const int c  = tid >> 2;
        const int jj = tid & 3;
        const float* src = x + ((size_t)b * C_ + c) * V_ + v0 + jj * 8;
        float4 f0 = ((const float4*)src)[0];
        float4 f1 = ((const float4*)src)[1];
        t[c][jj*8+0] = f0.x; t[c][jj*8+1] = f0.y; t[c][jj*8+2] = f0.z; t[c][jj*8+3] = f0.w;
        t[c][jj*8+4] = f1.x; t[c][jj*8+5] = f1.y; t[c][jj*8+6] = f1.z; t[c][jj*8+7] = f1.w;
    }
    __syncthreads();
    {
        const int vl = tid & 31;
        const int cg = tid >> 5;
        union { ushort u[8]; uint4 v4; } pk;
#pragma unroll
        for (int i = 0; i < 8; ++i) pk.u[i] = f2bf(t[cg*8 + i][vl]);
        *(uint4*)(xTb + ((size_t)(b * V_ + v0 + vl)) * 64 + cg * 8) = pk.v4;
    }
}

// K0b: Wtb[o][k' = t*64 + c] = bf16(W[o][c*9 + t])
__global__ __launch_bounds__(256) void k_tw(const float* __restrict__ W,
                                            ushort* __restrict__ Wtb) {
    int gid = blockIdx.x * 256 + threadIdx.x;
    if (gid >= O_ * K_) return;
    int o = gid / K_, kp = gid % K_;
    int tt = kp >> 6, c = kp & 63;
    Wtb[gid] = f2bf(W[o * K_ + c * L_ + tt]);
}

// ---------------------------------------------------------------------------
// K1: MFMA conv. 512 thr (8 waves), 16 v, all 16 b (256 n-rows), all 64 o.
// K' = t*64+c, 9 t-iters x 2 K-steps, double-buffered LDS, depth-2 prefetch,
// raw s_barrier + counted vmcnt (prefetch loads stay in flight across barriers).
template<bool BF16Y>
__global__ __launch_bounds__(512, 4) void k_conv(const ushort* __restrict__ xTb,
                                                 const int*    __restrict__ S,
                                                 const ushort* __restrict__ Wtb,
                                                 const float*  __restrict__ bias,
                                                 float*  __restrict__ out,
                                                 ushort* __restrict__ yb,
                                                 float* __restrict__ ps,
                                                 float* __restrict__ pq) {
    __shared__ char lds[45056];
    char* nbA = lds;            char* wbA = lds + 16384;
    char* nbB = lds + 20480;    char* wbB = lds + 36864;
    float* sA = (float*)(lds + 40960);   // [64][8]
    float* sQ = (float*)(lds + 43008);   // [64][8]

    const int tid = threadIdx.x;
    const int v0  = blockIdx.x * 16;
    // neigh staging: 2 threads/row, 256 rows
    const int srow = tid >> 1;
    const int h    = tid & 1;
    const int sb   = srow >> 4;
    const int sv   = v0 + (srow & 15);
    const int swzn = (srow >> 1) & 3;
    // W staging: all 512 threads, uint2 (8 B) each -> uniform 6 loads/thread/LD
    const int wso  = tid >> 3;            // o row 0..63
    const int wsl  = tid & 7;             // 8 B slot 0..7
    const int swzo = (wso >> 1) & 3;
    // mfma ids
    const int w = tid >> 6;
    const int l = tid & 63;
    const int q = l >> 4;
    const int r = l & 15;
    const int fswz = (r >> 1) & 3;

    // preload gather indices (removes dependent S load from steady-state loop)
    int gt[L_];
#pragma unroll
    for (int t = 0; t < L_; ++t) gt[t] = S[t * V_ + sv];

    f32x4 acc[2][4];
#pragma unroll
    for (int nt = 0; nt < 2; ++nt)
#pragma unroll
        for (int ot = 0; ot < 4; ++ot) acc[nt][ot] = (f32x4){0.f, 0.f, 0.f, 0.f};

    uint4 rn[2][4];
    uint2 rwv[2][2];

    auto LD = [&](int i, int set) {
        const uint4* p = (const uint4*)(xTb + ((size_t)sb * V_ + gt[i]) * 64 + h * 16);
        rn[set][0] = p[0]; rn[set][1] = p[1];   // step even (c 0..31)
        rn[set][2] = p[4]; rn[set][3] = p[5];   // step odd  (c 32..63)
        const uint2* wp = (const uint2*)(Wtb + (size_t)wso * K_ + i * 64 + wsl * 4);
        rwv[set][0] = wp[0];                    // step even
        rwv[set][1] = wp[8];                    // step odd (+64 B)
    };
    auto WRN = [&](char* nb, uint4 a, uint4 b2) {
        char* base = nb + srow * 64;
        *(uint4*)(base + ((( 2*h   ) ^ swzn) << 4)) = a;
        *(uint4*)(base + (((2*h + 1) ^ swzn) << 4)) = b2;
    };
    auto WRW = [&](char* wb, uint2 a) {
        const int pos16 = (wsl >> 1) ^ swzo;
        *(uint2*)(wb + wso * 64 + (pos16 << 4) + ((wsl & 1) << 3)) = a;
    };
    auto MM = [&](const char* nb, const char* wb) {
        bf16x8 a0 = *(const bf16x8*)(nb + (w*32      + r) * 64 + ((q ^ fswz) << 4));
        bf16x8 a1 = *(const bf16x8*)(nb + (w*32 + 16 + r) * 64 + ((q ^ fswz) << 4));
#pragma unroll
        for (int ot = 0; ot < 4; ++ot) {
            bf16x8 bo = *(const bf16x8*)(wb + (ot*16 + r) * 64 + ((q ^ fswz) << 4));
            acc[0][ot] = __builtin_amdgcn_mfma_f32_16x16x32_bf16(a0, bo, acc[0][ot], 0, 0, 0);
            acc[1][ot] = __builtin_amdgcn_mfma_f32_16x16x32_bf16(a1, bo, acc[1][ot], 0, 0, 0);
        }
    };

    LD(0, 0);
    LD(1, 1);

#define CONV_ITER(I, VMN)                                                    \
    {                                                                        \
        constexpr int set = (I) & 1;                                         \
        VMW(VMN);                       /* LD(I) arrived; LD(I+1) in flight */\
        WRN(nbA, rn[set][0], rn[set][1]); WRW(wbA, rwv[set][0]);             \
        BARRIER();                                                           \
        MM(nbA, wbA);                                                        \
        WRN(nbB, rn[set][2], rn[set][3]); WRW(wbB, rwv[set][1]);             \
        if ((I) < 7) LD((I) + 2, set);  /* depth-2 prefetch */               \
        BARRIER();                                                           \
        MM(nbB, wbB);                                                        \
    }

    CONV_ITER(0, 6)
    CONV_ITER(1, 6)
    CONV_ITER(2, 6)
    CONV_ITER(3, 6)
    CONV_ITER(4, 6)
    CONV_ITER(5, 6)
    CONV_ITER(6, 6)
    CONV_ITER(7, 6)
    CONV_ITER(8, 0)
#undef CONV_ITER

    // epilogue: y = acc + bias -> store (bf16 or f32) + fused partial stats
    const int vbase = v0 + q * 4;
    float ssum[4] = {0.f, 0.f, 0.f, 0.f};
    float qsum[4] = {0.f, 0.f, 0.f, 0.f};
#pragma unroll
    for (int ot = 0; ot < 4; ++ot) {
        const int o = ot * 16 + r;
        const float bo = bias[o];
#pragma unroll
        for (int nt = 0; nt < 2; ++nt) {
            const int b = 2 * w + nt;
            float4 y;
            y.x = acc[nt][ot][0] + bo;
            y.y = acc[nt][ot][1] + bo;
            y.z = acc[nt][ot][2] + bo;
            y.w = acc[nt][ot][3] + bo;
            if (BF16Y) {
                ushort4 u;
                u.x = f2bf(y.x); u.y = f2bf(y.y); u.z = f2bf(y.z); u.w = f2bf(y.w);
                *(ushort4*)(yb + ((size_t)(b * O_ + o)) * V_ + vbase) = u;
            } else {
                *(float4*)(out + ((size_t)(b * O_ + o)) * V_ + vbase) = y;
            }
            ssum[ot] += y.x + y.y + y.z + y.w;
            qsum[ot] += y.x*y.x + y.y*y.y + y.z*y.z + y.w*y.w;
        }
    }
#pragma unroll
    for (int ot = 0; ot < 4; ++ot) {
        float s  = ssum[ot], qq = qsum[ot];
        s  += __shfl_xor(s, 16);  s  += __shfl_xor(s, 32);
        qq += __shfl_xor(qq, 16); qq += __shfl_xor(qq, 32);
        if (l < 16) { sA[(ot*16 + l) * 8 + w] = s; sQ[(ot*16 + l) * 8 + w] = qq; }
    }
    __syncthreads();
    if (tid < 64) {
        float s = 0.f, qq = 0.f;
#pragma unroll
        for (int j = 0; j < 8; ++j) { s += sA[tid*8 + j]; qq += sQ[tid*8 + j]; }
        ps[blockIdx.x * 64 + tid] = s;
        pq[blockIdx.x * 64 + tid] = qq;
    }
}

// ---------------------------------------------------------------------------
// K2: reduce 1250 block-partials per o -> scale/shift
__global__ __launch_bounds__(256) void k_fin(const float* __restrict__ ps,
                                             const float* __restrict__ pq,
                                             const float* __restrict__ gamma,
                                             const float* __restrict__ beta,
                                             float* __restrict__ ss) {
    __shared__ float as_[4], aq_[4];
    const int o = blockIdx.x, tid = threadIdx.x;
    float s = 0.f, q = 0.f;
    for (int i = tid; i < 1250; i += 256) { s += ps[i*64 + o]; q += pq[i*64 + o]; }
#pragma unroll
    for (int off = 1; off < 64; off <<= 1) { s += __shfl_xor(s, off); q += __shfl_xor(q, off); }
    if ((tid & 63) == 0) { as_[tid >> 6] = s; aq_[tid >> 6] = q; }
    __syncthreads();
    if (tid == 0) {
        float S4 = as_[0] + as_[1] + as_[2] + as_[3];
        float Q4 = aq_[0] + aq_[1] + aq_[2] + aq_[3];
        const float n = 1.f / (float)NBV;
        float mean = S4 * n;
        float var  = fmaxf(Q4 * n - mean * mean, 0.f);
        float sc   = gamma[o] * rsqrtf(var + 1e-5f);
        ss[o]      = sc;
        ss[O_ + o] = beta[o] - mean * sc;
    }
}

// K3a: normalize + relu from bf16 y -> f32 out
__global__ __launch_bounds__(256) void k_norm_bf(const ushort* __restrict__ yb,
                                                 float* __restrict__ out,
                                                 const float* __restrict__ ss) {
    const int stride = gridDim.x * blockDim.x;
    const int total8 = (B_ * O_ * V_) / 8;
    for (int i = blockIdx.x * blockDim.x + threadIdx.x; i < total8; i += stride) {
        uint4 raw = ((const uint4*)yb)[i];
        const int row = (i * 8) / V_;
        const int o   = row & 63;
        const float sc = ss[o], sh = ss[O_ + o];
        const uint u32[4] = {raw.x, raw.y, raw.z, raw.w};
        float4 o0, o1;
        float vals[8];
#pragma unroll
        for (int j = 0; j < 4; ++j) {
            union { uint u; float f; } lo, hi;
            lo.u = (u32[j] & 0xffffu) << 16;
            hi.u = (u32[j] & 0xffff0000u);
            vals[2*j]   = lo.f;
            vals[2*j+1] = hi.f;
        }
        o0.x = fmaxf(fmaf(vals[0], sc, sh), 0.f);
        o0.y = fmaxf(fmaf(vals[1], sc, sh), 0.f);
        o0.z = fmaxf(fmaf(vals[2], sc, sh), 0.f);
        o0.w = fmaxf(fmaf(vals[3], sc, sh), 0.f);
        o1.x = fmaxf(fmaf(vals[4], sc, sh), 0.f);
        o1.y = fmaxf(fmaf(vals[5], sc, sh), 0.f);
        o1.z = fmaxf(fmaf(vals[6], sc, sh), 0.f);
        o1.w = fmaxf(fmaf(vals[7], sc, sh), 0.f);
        ((float4*)out)[2*i]   = o0;
        ((float4*)out)[2*i+1] = o1;
    }
}

// K3b: fallback, in-place f32 normalize + relu
__global__ __launch_bounds__(256) void k_norm_f32(float* __restrict__ out,
                                                  const float* __restrict__ ss) {
    const int stride = gridDim.x * blockDim.x;
    const int total4 = (B_ * O_ * V_) / 4;
    for (int i = blockIdx.x * blockDim.x + threadIdx.x; i < total4; i += stride) {
        float4 v4 = ((const float4*)out)[i];
        const int row = (i * 4) / V_;
        const int o   = row & 63;
        const float sc = ss[o], sh = ss[O_ + o];
        v4.x = fmaxf(fmaf(v4.x, sc, sh), 0.f);
        v4.y = fmaxf(fmaf(v4.y, sc, sh), 0.f);
        v4.z = fmaxf(fmaf(v4.z, sc, sh), 0.f);
        v4.w = fmaxf(fmaf(v4.w, sc, sh), 0.f);
        ((float4*)out)[i] = v4;
    }
}

// ---------------------------------------------------------------------------
extern "C" void kernel_launch(void* const* d_in, const int* in_sizes, int n_in,
                              void* d_out, int out_size, void* d_ws, size_t ws_size,
                              hipStream_t stream) {
    const float* x     = (const float*)d_in[0];
    const int*   S     = (const int*)  d_in[1];
    const float* W     = (const float*)d_in[2];
    const float* bias  = (const float*)d_in[3];
    const float* gamma = (const float*)d_in[4];
    const float* beta  = (const float*)d_in[5];
    float* out = (float*)d_out;

    char* ws = (char*)d_ws;
    const size_t xT_b = 40960000;            // 16*20000*64*2
    const size_t wt_b = 73728;               // 576*64*2
    const size_t yb_b = 40960000;            // 16*64*20000*2
    const size_t ps_b = 320000;              // 1250*64*4

    ushort* xTb = (ushort*)(ws);
    ushort* Wtb = (ushort*)(ws + xT_b);
    const bool bf16y = ws_size >= xT_b + wt_b + yb_b + 2 * ps_b + 512;

    ushort* yb; float* ps; float* pq; float* ssb;
    if (bf16y) {
        yb  = (ushort*)(ws + xT_b + wt_b);
        ps  = (float*) (ws + xT_b + wt_b + yb_b);
        pq  = (float*) (ws + xT_b + wt_b + yb_b + ps_b);
        ssb = (float*) (ws + xT_b + wt_b + yb_b + 2 * ps_b);
    } else {
        yb  = nullptr;
        ps  = (float*) (ws + xT_b + wt_b);
        pq  = (float*) (ws + xT_b + wt_b + ps_b);
        ssb = (float*) (ws + xT_b + wt_b + 2 * ps_b);
    }

    k_tw<<<dim3((O_ * K_ + 255) / 256), dim3(256), 0, stream>>>(W, Wtb);
    k_tx<<<dim3(625, 16),               dim3(256), 0, stream>>>(x, xTb);
    if (bf16y) {
        k_conv<true ><<<dim3(V_ / 16), dim3(512), 0, stream>>>(xTb, S, Wtb, bias, out, yb, ps, pq);
        k_fin<<<dim3(64), dim3(256), 0, stream>>>(ps, pq, gamma, beta, ssb);
        k_norm_bf<<<dim3(2048), dim3(256), 0, stream>>>(yb, out, ssb);
    } else {
        k_conv<false><<<dim3(V_ / 16), dim3(512), 0, stream>>>(xTb, S, Wtb, bias, out, yb, ps, pq);
        k_fin<<<dim3(64), dim3(256), 0, stream>>>(ps, pq, gamma, beta, ssb);
        k_norm_f32<<<dim3(2048), dim3(256), 0, stream>>>(out, ssb);
    }
}